// Round 3
// baseline (7302.959 us; speedup 1.0000x reference)
//
#include <hip/hip_runtime.h>
#include <hip/hip_bf16.h>

#define TT 512
#define NB 1024

typedef float f32x4 __attribute__((ext_vector_type(4)));
typedef __bf16 bf16x8 __attribute__((ext_vector_type(8)));

// ---- workspace layout (bf16 elems). All matrices stored as A-fragments for
// the TRANSPOSED GEMM  C^T[feature][batch] = W^T @ act^T :
//   frag(mt, kt, lane, j) = W[kappa][16*mt + (lane&15)]
// where for weights consuming register-resident activations (Whp, Wm, Whpost,
// Wr1) kappa = 32*kt + 16*(j>>2) + 4*(lane>>4) + (j&3)   [the pi-permutation
// that makes B-frags == accumulator contents], and for Wcp (consumes x from
// memory) kappa = 32*kt + 8*(lane>>4) + j (natural).
#define OFF_HP 0
#define OFF_CP 65536
#define OFF_M  81920
#define OFF_PO 212992
#define OFF_R1 278528
#define TOT    344064

__global__ __launch_bounds__(256) void pack_weights(
    const float* __restrict__ Whp, const float* __restrict__ Wm,
    const float* __restrict__ Wcp, const float* __restrict__ Whpost,
    const float* __restrict__ Wr1, __bf16* __restrict__ wsp) {
  int id = blockIdx.x * 256 + threadIdx.x;
  if (id >= TOT) return;
  int j = id & 7, lane = (id >> 3) & 63;
  int lq = lane >> 4, l15 = lane & 15;
  int rel, KT; const float* W; bool perm = true;
  if (id < OFF_CP)      { rel = id;          KT = 8;  W = Whp; }
  else if (id < OFF_M)  { rel = id - OFF_CP; KT = 2;  W = Wcp; perm = false; }
  else if (id < OFF_PO) { rel = id - OFF_M;  KT = 16; W = Wm; }
  else if (id < OFF_R1) { rel = id - OFF_PO; KT = 8;  W = Whpost; }
  else                  { rel = id - OFF_R1; KT = 8;  W = Wr1; }
  int ktm = rel >> 9;
  int kt = ktm % KT, mt = ktm / KT;
  int phi = 16 * mt + l15;
  int kk;
  if (perm) {
    int kb = (kt >= 8) ? kt - 8 : kt;          // only mesh has kt>=8
    kk = 32 * kb + 16 * (j >> 2) + 4 * lq + (j & 3);
    if (kt >= 8) kk += 256;                    // cp half of the concat
  } else {
    kk = 32 * kt + 8 * lq + j;
  }
  wsp[id] = (__bf16)W[kk * 256 + phi];
}

__device__ __forceinline__ float tanh_fast(float x) {
  float t = __expf(2.0f * x);
  return 1.0f - __fdividef(2.0f, t + 1.0f);
}

// acc[mi] covers m-tile (mt0+mi); kt-outer / mi-inner keeps consecutive MFMAs
// on independent accumulator chains (4-way ILP into the matrix pipe).
template<int KT>
__device__ __forceinline__ void gemm_tx(f32x4 acc[4], const __bf16* __restrict__ Wst,
                                        const bf16x8* B, int mt0, int lane) {
  const __bf16* base = Wst + (size_t)(mt0 * KT) * 512 + lane * 8;
  #pragma unroll
  for (int kt = 0; kt < KT; ++kt)
    #pragma unroll
    for (int mi = 0; mi < 4; ++mi) {
      bf16x8 af = *(const bf16x8*)(base + (mi * KT + kt) * 512);
      acc[mi] = __builtin_amdgcn_mfma_f32_16x16x32_bf16(af, B[kt], acc[mi], 0, 0, 0);
    }
}

template<int KT>
__device__ __forceinline__ void read_B(bf16x8* B, const __bf16* tile, int lane) {
  #pragma unroll
  for (int kt = 0; kt < KT; ++kt)
    B[kt] = *(const bf16x8*)(tile + kt * 512 + lane * 8);
}

// tanh + bf16-pack this wave's 4 m-tiles into B-fragments kt = ktb, ktb+1.
// Pure in-lane: B[kt][j] = tanh(acc[2*(kt-ktb) + (j>>2)][j&3]). Conflict-free
// ds_write_b128 at lane*16.
__device__ __forceinline__ void pack_tanh(__bf16* region, int ktb,
                                          const f32x4 a[4], int lane) {
  #pragma unroll
  for (int h = 0; h < 2; ++h) {
    bf16x8 f;
    #pragma unroll
    for (int r = 0; r < 4; ++r) {
      f[r]     = (__bf16)tanh_fast(a[2 * h][r]);
      f[4 + r] = (__bf16)tanh_fast(a[2 * h + 1][r]);
    }
    *(bf16x8*)(region + (ktb + h) * 512 + lane * 8) = f;
  }
}

__global__ __launch_bounds__(256, 1) void rnn_seq(
    const float* __restrict__ x, const __bf16* __restrict__ wsp,
    const float* __restrict__ bhp, const float* __restrict__ bcp,
    const float* __restrict__ bm, const float* __restrict__ bhpost,
    const float* __restrict__ br1, const float* __restrict__ Wr2,
    const float* __restrict__ br2, float* __restrict__ out) {
  __shared__ __align__(16) __bf16 hB[8 * 512];   // h state as B-frags
  __shared__ __align__(16) __bf16 mB[16 * 512];  // [hpB | cpB] for mesh
  __shared__ __align__(16) __bf16 uB[8 * 512];   // mesh output
  __shared__ float outp[64];

  const int tid  = threadIdx.x;
  const int wv   = tid >> 6;      // 0..3, owns m-tiles 4wv..4wv+3
  const int lane = tid & 63;
  const int lq   = lane >> 4, l15 = lane & 15;
  const int n0   = blockIdx.x * 16;
  const int mt0  = 4 * wv;

  // per-lane bias / Wr2 fragments: element (mi, r) <-> feature 16*(mt0+mi)+4*lq+r
  f32x4 b_hp[4], b_cp[4], b_m[4], b_po[4], b_r1[4], w2v[4];
  #pragma unroll
  for (int mi = 0; mi < 4; ++mi) {
    int o = 16 * (mt0 + mi) + 4 * lq;
    b_hp[mi] = *(const f32x4*)(bhp + o);
    b_cp[mi] = *(const f32x4*)(bcp + o);
    b_m [mi] = *(const f32x4*)(bm + o);
    b_po[mi] = *(const f32x4*)(bhpost + o);
    b_r1[mi] = *(const f32x4*)(br1 + o);
    w2v [mi] = *(const f32x4*)(Wr2 + o);
  }
  const float br2v = br2[0];
  for (int i = tid; i < 8 * 512; i += 256) hB[i] = (__bf16)0.0f;  // h0 = 0
  __syncthreads();

  // x for step t, prefetched one step ahead (issued in stage 3)
  const float* xbase = x + (size_t)(n0 + l15) * 64 + 8 * lq;
  f32x4 xr[4];
  xr[0] = *(const f32x4*)(xbase);      xr[1] = *(const f32x4*)(xbase + 4);
  xr[2] = *(const f32x4*)(xbase + 32); xr[3] = *(const f32x4*)(xbase + 36);

  for (int t = 0; t < TT; ++t) {
    bf16x8 Bx[2];
    #pragma unroll
    for (int j = 0; j < 4; ++j) {
      Bx[0][j] = (__bf16)xr[0][j]; Bx[0][4 + j] = (__bf16)xr[1][j];
      Bx[1][j] = (__bf16)xr[2][j]; Bx[1][4 + j] = (__bf16)xr[3][j];
    }

    // ---- stage 1: hp = h@Whp+bhp ; cp = x@Wcp+bcp ; r1(h) for out[t-1] ----
    bf16x8 Bh[8];
    read_B<8>(Bh, hB, lane);
    f32x4 ah[4], ar[4], ac[4];
    #pragma unroll
    for (int mi = 0; mi < 4; ++mi) { ah[mi] = b_hp[mi]; ar[mi] = b_r1[mi]; ac[mi] = b_cp[mi]; }
    gemm_tx<8>(ah, wsp + OFF_HP, Bh, mt0, lane);
    gemm_tx<8>(ar, wsp + OFF_R1, Bh, mt0, lane);
    gemm_tx<2>(ac, wsp + OFF_CP, Bx, mt0, lane);
    pack_tanh(mB,           2 * wv, ah, lane);
    pack_tanh(mB + 8 * 512, 2 * wv, ac, lane);
    {
      float p = 0.f;
      #pragma unroll
      for (int mi = 0; mi < 4; ++mi)
        #pragma unroll
        for (int r = 0; r < 4; ++r)
          p += fmaxf(ar[mi][r], 0.f) * w2v[mi][r];
      p += __shfl_xor(p, 16, 64);
      p += __shfl_xor(p, 32, 64);
      if (lane < 16) outp[wv * 16 + lane] = p;
    }
    __syncthreads();  // B1

    // ---- stage 2: u = cat @ Wm + bm ----
    if (t > 0 && tid < 16)
      out[(size_t)(t - 1) * NB + n0 + tid] =
          outp[tid] + outp[16 + tid] + outp[32 + tid] + outp[48 + tid] + br2v;
    bf16x8 Bm[16];
    read_B<16>(Bm, mB, lane);
    f32x4 am[4];
    #pragma unroll
    for (int mi = 0; mi < 4; ++mi) am[mi] = b_m[mi];
    gemm_tx<16>(am, wsp + OFF_M, Bm, mt0, lane);
    pack_tanh(uB, 2 * wv, am, lane);
    __syncthreads();  // B2

    // ---- stage 3: h = tanh(u @ Whpost + bhpost) ; prefetch x[t+1] ----
    bf16x8 Bu[8];
    read_B<8>(Bu, uB, lane);
    f32x4 ap[4];
    #pragma unroll
    for (int mi = 0; mi < 4; ++mi) ap[mi] = b_po[mi];
    {
      int tn = (t + 1 < TT) ? t + 1 : TT - 1;
      const float* xp = xbase + (size_t)tn * NB * 64;
      xr[0] = *(const f32x4*)(xp);      xr[1] = *(const f32x4*)(xp + 4);
      xr[2] = *(const f32x4*)(xp + 32); xr[3] = *(const f32x4*)(xp + 36);
    }
    gemm_tx<8>(ap, wsp + OFF_PO, Bu, mt0, lane);
    pack_tanh(hB, 2 * wv, ap, lane);
    __syncthreads();  // B3
  }

  // ---- tail: regressor on final h ----
  {
    bf16x8 Bh[8];
    read_B<8>(Bh, hB, lane);
    f32x4 ar[4];
    #pragma unroll
    for (int mi = 0; mi < 4; ++mi) ar[mi] = b_r1[mi];
    gemm_tx<8>(ar, wsp + OFF_R1, Bh, mt0, lane);
    float p = 0.f;
    #pragma unroll
    for (int mi = 0; mi < 4; ++mi)
      #pragma unroll
      for (int r = 0; r < 4; ++r)
        p += fmaxf(ar[mi][r], 0.f) * w2v[mi][r];
    p += __shfl_xor(p, 16, 64);
    p += __shfl_xor(p, 32, 64);
    if (lane < 16) outp[wv * 16 + lane] = p;
    __syncthreads();
    if (tid < 16)
      out[(size_t)(TT - 1) * NB + n0 + tid] =
          outp[tid] + outp[16 + tid] + outp[32 + tid] + outp[48 + tid] + br2v;
  }
}

extern "C" void kernel_launch(void* const* d_in, const int* in_sizes, int n_in,
                              void* d_out, int out_size, void* d_ws, size_t ws_size,
                              hipStream_t stream) {
  const float* x      = (const float*)d_in[0];
  const float* Whp    = (const float*)d_in[1];
  const float* bhp    = (const float*)d_in[2];
  const float* Wcp    = (const float*)d_in[3];
  const float* bcp    = (const float*)d_in[4];
  const float* Wm     = (const float*)d_in[5];
  const float* bm     = (const float*)d_in[6];
  const float* Whpost = (const float*)d_in[7];
  const float* bhpost = (const float*)d_in[8];
  const float* Wr1    = (const float*)d_in[9];
  const float* br1    = (const float*)d_in[10];
  const float* Wr2    = (const float*)d_in[11];
  const float* br2    = (const float*)d_in[12];
  __bf16* wsp = (__bf16*)d_ws;
  float*  out = (float*)d_out;

  if (ws_size < (size_t)TOT * sizeof(__bf16)) return;

  pack_weights<<<(TOT + 255) / 256, 256, 0, stream>>>(Whp, Wm, Wcp, Whpost, Wr1, wsp);
  rnn_seq<<<64, 256, 0, stream>>>(x, wsp, bhp, bcp, bm, bhpost, br1, Wr2, br2, out);
}

// Round 4
// 6653.618 us; speedup vs baseline: 1.0976x; 1.0976x over previous
//
#include <hip/hip_runtime.h>
#include <hip/hip_bf16.h>

#define TT 512
#define NB 1024

typedef float f32x4 __attribute__((ext_vector_type(4)));
typedef __bf16 bf16x8 __attribute__((ext_vector_type(8)));

// ---- workspace layout (bf16 elems). All matrices stored as A-fragments for
// the TRANSPOSED GEMM  C^T[feature][batch] = W^T @ act^T :
//   frag(mt, kt, lane, j) at ((mt*KT + kt)*512 + lane*8 + j)
//   value = W[kappa][16*mt + (lane&15)]
// For weights consuming register-resident activations (Whp, Wm, Whpost, Wr1):
//   kappa = 32*kt + 16*(j>>2) + 4*(lane>>4) + (j&3)  [pi-permutation: B-frag ==
//   accumulator contents of the producing stage]. For Wcp (consumes x):
//   kappa = 32*kt + 8*(lane>>4) + j (natural).
#define OFF_HP 0
#define OFF_CP 65536
#define OFF_M  81920
#define OFF_PO 212992
#define OFF_R1 278528
#define TOT    344064

__global__ __launch_bounds__(256) void pack_weights(
    const float* __restrict__ Whp, const float* __restrict__ Wm,
    const float* __restrict__ Wcp, const float* __restrict__ Whpost,
    const float* __restrict__ Wr1, __bf16* __restrict__ wsp) {
  int id = blockIdx.x * 256 + threadIdx.x;
  if (id >= TOT) return;
  int j = id & 7, lane = (id >> 3) & 63;
  int lq = lane >> 4, l15 = lane & 15;
  int rel, KT; const float* W; bool perm = true;
  if (id < OFF_CP)      { rel = id;          KT = 8;  W = Whp; }
  else if (id < OFF_M)  { rel = id - OFF_CP; KT = 2;  W = Wcp; perm = false; }
  else if (id < OFF_PO) { rel = id - OFF_M;  KT = 16; W = Wm; }
  else if (id < OFF_R1) { rel = id - OFF_PO; KT = 8;  W = Whpost; }
  else                  { rel = id - OFF_R1; KT = 8;  W = Wr1; }
  int ktm = rel >> 9;
  int kt = ktm % KT, mt = ktm / KT;
  int phi = 16 * mt + l15;
  int kk;
  if (perm) {
    int kb = (kt >= 8) ? kt - 8 : kt;          // only mesh has kt>=8
    kk = 32 * kb + 16 * (j >> 2) + 4 * lq + (j & 3);
    if (kt >= 8) kk += 256;                    // cp half of the concat
  } else {
    kk = 32 * kt + 8 * lq + j;
  }
  wsp[id] = (__bf16)W[kk * 256 + phi];
}

__device__ __forceinline__ float tanh_fast(float x) {
  float t = __expf(2.0f * x);
  return 1.0f - __fdividef(2.0f, t + 1.0f);
}

#define MFMA(a, b, c) __builtin_amdgcn_mfma_f32_16x16x32_bf16((a), (b), (c), 0, 0, 0)

// tanh + pack this wave's two accumulators into ONE B-fragment (kt = wv).
// Pure in-lane: B[wv][j] = tanh(acc[j>>2][j&3]). Conflict-free ds_write_b128.
__device__ __forceinline__ void pack2(__bf16* region, int wv, int lane,
                                      const f32x4& a0, const f32x4& a1) {
  bf16x8 f;
  #pragma unroll
  for (int r = 0; r < 4; ++r) {
    f[r]     = (__bf16)tanh_fast(a0[r]);
    f[4 + r] = (__bf16)tanh_fast(a1[r]);
  }
  *(bf16x8*)(region + wv * 512 + lane * 8) = f;
}

__global__ __launch_bounds__(512, 2) void rnn_seq(
    const float* __restrict__ x, const __bf16* __restrict__ wsp,
    const float* __restrict__ bhp, const float* __restrict__ bcp,
    const float* __restrict__ bm, const float* __restrict__ bhpost,
    const float* __restrict__ br1, const float* __restrict__ Wr2,
    const float* __restrict__ br2, float* __restrict__ out) {
  __shared__ __align__(16) __bf16 hB[8 * 512];   // h state as B-frags
  __shared__ __align__(16) __bf16 mB[16 * 512];  // [hpB | cpB] for mesh
  __shared__ __align__(16) __bf16 uB[8 * 512];   // mesh output
  __shared__ float lb[6 * 256];                  // bhp,bcp,bm,bhpost,br1,Wr2
  __shared__ float outp[128];

  const int tid  = threadIdx.x;
  const int wv   = tid >> 6;      // 0..7, owns m-tiles 2wv, 2wv+1
  const int lane = tid & 63;
  const int lq   = lane >> 4, l15 = lane & 15;
  const int n0   = blockIdx.x * 16;
  const int mt0  = 2 * wv;

  if (tid < 256) {
    lb[0 * 256 + tid] = bhp[tid];
    lb[1 * 256 + tid] = bcp[tid];
    lb[2 * 256 + tid] = bm[tid];
    lb[3 * 256 + tid] = bhpost[tid];
    lb[4 * 256 + tid] = br1[tid];
    lb[5 * 256 + tid] = Wr2[tid];
  }
  for (int i = tid; i < 8 * 512; i += 512) hB[i] = (__bf16)0.0f;  // h0 = 0
  const float br2v = br2[0];

  // bias/Wr2 accessor: element r of f32x4 <-> feature 16*mt + 4*lq + r
  #define BIAS(a, m) (*(const f32x4*)(lb + (a) * 256 + (m) * 16 + 4 * lq))
  const f32x4 w2a = *(const f32x4*)(Wr2 + mt0 * 16 + 4 * lq);
  const f32x4 w2b = *(const f32x4*)(Wr2 + (mt0 + 1) * 16 + 4 * lq);

  // ---- register-resident mesh weights: 32 frags = 128 VGPRs ----
  bf16x8 wm0[16], wm1[16];
  {
    const __bf16* mp = wsp + OFF_M + (size_t)(mt0 * 16) * 512 + lane * 8;
    #pragma unroll
    for (int kt = 0; kt < 16; ++kt) {
      wm0[kt] = *(const bf16x8*)(mp + kt * 512);
      wm1[kt] = *(const bf16x8*)(mp + (16 + kt) * 512);
    }
  }

  const __bf16* hp_p = wsp + OFF_HP + (size_t)(mt0 * 8) * 512 + lane * 8;
  const __bf16* r1_p = wsp + OFF_R1 + (size_t)(mt0 * 8) * 512 + lane * 8;
  const __bf16* cp_p = wsp + OFF_CP + (size_t)(mt0 * 2) * 512 + lane * 8;
  const __bf16* po_p = wsp + OFF_PO + (size_t)(mt0 * 8) * 512 + lane * 8;

  __syncthreads();

  // x for step t (prefetched one step ahead during stage 2)
  const float* xbase = x + (size_t)(n0 + l15) * 64 + 8 * lq;
  f32x4 xr0 = *(const f32x4*)(xbase);
  f32x4 xr1 = *(const f32x4*)(xbase + 4);
  f32x4 xr2 = *(const f32x4*)(xbase + 32);
  f32x4 xr3 = *(const f32x4*)(xbase + 36);

  for (int t = 0; t < TT; ++t) {
    bf16x8 Bx0, Bx1;
    #pragma unroll
    for (int j = 0; j < 4; ++j) {
      Bx0[j] = (__bf16)xr0[j]; Bx0[4 + j] = (__bf16)xr1[j];
      Bx1[j] = (__bf16)xr2[j]; Bx1[4 + j] = (__bf16)xr3[j];
    }

    // ---- stage 1: hp = h@Whp+bhp ; r1(h) for out[t-1] ; cp = x@Wcp+bcp ----
    bf16x8 cpb[4];
    #pragma unroll
    for (int p = 0; p < 4; ++p) cpb[p] = *(const bf16x8*)(cp_p + p * 512);
    bf16x8 hpb[4], r1b[4];
    #pragma unroll
    for (int p = 0; p < 4; ++p) {
      hpb[p] = *(const bf16x8*)(hp_p + p * 512);
      r1b[p] = *(const bf16x8*)(r1_p + p * 512);
    }
    bf16x8 Bh[8];
    #pragma unroll
    for (int kt = 0; kt < 8; ++kt)
      Bh[kt] = *(const bf16x8*)(hB + kt * 512 + lane * 8);

    f32x4 ah0 = BIAS(0, mt0), ah1 = BIAS(0, mt0 + 1);
    f32x4 ar0 = BIAS(4, mt0), ar1 = BIAS(4, mt0 + 1);
    #pragma unroll
    for (int i = 0; i < 16; ++i) {       // frag i = (mt0 + (i>>3), kt = i&7)
      int kt = i & 7;
      bf16x8 a1 = hpb[i & 3], a2 = r1b[i & 3];
      if (i < 8) { ah0 = MFMA(a1, Bh[kt], ah0); ar0 = MFMA(a2, Bh[kt], ar0); }
      else       { ah1 = MFMA(a1, Bh[kt], ah1); ar1 = MFMA(a2, Bh[kt], ar1); }
      if (i + 4 < 16) {                  // rolling depth-4 prefetch
        hpb[i & 3] = *(const bf16x8*)(hp_p + (i + 4) * 512);
        r1b[i & 3] = *(const bf16x8*)(r1_p + (i + 4) * 512);
      }
    }
    f32x4 ac0 = BIAS(1, mt0), ac1 = BIAS(1, mt0 + 1);
    ac0 = MFMA(cpb[0], Bx0, ac0); ac0 = MFMA(cpb[1], Bx1, ac0);
    ac1 = MFMA(cpb[2], Bx0, ac1); ac1 = MFMA(cpb[3], Bx1, ac1);

    pack2(mB,           wv, lane, ah0, ah1);
    pack2(mB + 8 * 512, wv, lane, ac0, ac1);
    {
      float p = 0.f;
      #pragma unroll
      for (int r = 0; r < 4; ++r)
        p += fmaxf(ar0[r], 0.f) * w2a[r] + fmaxf(ar1[r], 0.f) * w2b[r];
      p += __shfl_xor(p, 16, 64);
      p += __shfl_xor(p, 32, 64);
      if (lane < 16) outp[wv * 16 + lane] = p;
    }
    __syncthreads();  // B1

    if (t > 0 && tid < 16) {
      float s = br2v;
      #pragma unroll
      for (int w = 0; w < 8; ++w) s += outp[w * 16 + tid];
      out[(size_t)(t - 1) * NB + n0 + tid] = s;
    }

    // ---- stage 2: u = cat @ Wm + bm  (weights resident — no loads) ----
    // prefetch stage-3 po frags + next step's x while the mesh MFMAs run
    bf16x8 pob[8];
    #pragma unroll
    for (int p = 0; p < 8; ++p) pob[p] = *(const bf16x8*)(po_p + p * 512);
    {
      int tn = (t + 1 < TT) ? t + 1 : TT - 1;
      const float* xp = xbase + (size_t)tn * NB * 64;
      xr0 = *(const f32x4*)(xp);      xr1 = *(const f32x4*)(xp + 4);
      xr2 = *(const f32x4*)(xp + 32); xr3 = *(const f32x4*)(xp + 36);
    }
    f32x4 am0 = BIAS(2, mt0), am1 = BIAS(2, mt0 + 1);
    #pragma unroll
    for (int kt = 0; kt < 16; ++kt) {
      bf16x8 Bm = *(const bf16x8*)(mB + kt * 512 + lane * 8);
      am0 = MFMA(wm0[kt], Bm, am0);
      am1 = MFMA(wm1[kt], Bm, am1);
    }
    pack2(uB, wv, lane, am0, am1);
    __syncthreads();  // B2

    // ---- stage 3: h = tanh(u @ Whpost + bhpost) ----
    bf16x8 Bu[8];
    #pragma unroll
    for (int kt = 0; kt < 8; ++kt)
      Bu[kt] = *(const bf16x8*)(uB + kt * 512 + lane * 8);
    f32x4 ap0 = BIAS(3, mt0), ap1 = BIAS(3, mt0 + 1);
    #pragma unroll
    for (int i = 0; i < 16; ++i) {
      int kt = i & 7;
      bf16x8 a = pob[i & 7];
      if (i < 8) ap0 = MFMA(a, Bu[kt], ap0);
      else       ap1 = MFMA(a, Bu[kt], ap1);
      if (i + 8 < 16) pob[i & 7] = *(const bf16x8*)(po_p + (i + 8) * 512);
    }
    pack2(hB, wv, lane, ap0, ap1);
    __syncthreads();  // B3
  }

  // ---- tail: regressor on final h ----
  {
    bf16x8 Bh[8];
    #pragma unroll
    for (int kt = 0; kt < 8; ++kt)
      Bh[kt] = *(const bf16x8*)(hB + kt * 512 + lane * 8);
    f32x4 ar0 = BIAS(4, mt0), ar1 = BIAS(4, mt0 + 1);
    #pragma unroll
    for (int i = 0; i < 16; ++i) {
      bf16x8 a = *(const bf16x8*)(r1_p + i * 512);
      if (i < 8) ar0 = MFMA(a, Bh[i & 7], ar0);
      else       ar1 = MFMA(a, Bh[i & 7], ar1);
    }
    float p = 0.f;
    #pragma unroll
    for (int r = 0; r < 4; ++r)
      p += fmaxf(ar0[r], 0.f) * w2a[r] + fmaxf(ar1[r], 0.f) * w2b[r];
    p += __shfl_xor(p, 16, 64);
    p += __shfl_xor(p, 32, 64);
    if (lane < 16) outp[wv * 16 + lane] = p;
    __syncthreads();
    if (tid < 16) {
      float s = br2v;
      #pragma unroll
      for (int w = 0; w < 8; ++w) s += outp[w * 16 + tid];
      out[(size_t)(TT - 1) * NB + n0 + tid] = s;
    }
  }
}

extern "C" void kernel_launch(void* const* d_in, const int* in_sizes, int n_in,
                              void* d_out, int out_size, void* d_ws, size_t ws_size,
                              hipStream_t stream) {
  const float* x      = (const float*)d_in[0];
  const float* Whp    = (const float*)d_in[1];
  const float* bhp    = (const float*)d_in[2];
  const float* Wcp    = (const float*)d_in[3];
  const float* bcp    = (const float*)d_in[4];
  const float* Wm     = (const float*)d_in[5];
  const float* bm     = (const float*)d_in[6];
  const float* Whpost = (const float*)d_in[7];
  const float* bhpost = (const float*)d_in[8];
  const float* Wr1    = (const float*)d_in[9];
  const float* br1    = (const float*)d_in[10];
  const float* Wr2    = (const float*)d_in[11];
  const float* br2    = (const float*)d_in[12];
  __bf16* wsp = (__bf16*)d_ws;
  float*  out = (float*)d_out;

  if (ws_size < (size_t)TOT * sizeof(__bf16)) return;

  pack_weights<<<(TOT + 255) / 256, 256, 0, stream>>>(Whp, Wm, Wcp, Whpost, Wr1, wsp);
  rnn_seq<<<64, 512, 0, stream>>>(x, wsp, bhp, bcp, bm, bhpost, br1, Wr2, br2, out);
}

// Round 5
// 6133.562 us; speedup vs baseline: 1.1907x; 1.0848x over previous
//
#include <hip/hip_runtime.h>
#include <hip/hip_bf16.h>

#define TT 512
#define NB 1024

typedef float f32x4 __attribute__((ext_vector_type(4)));
typedef __bf16 bf16x8 __attribute__((ext_vector_type(8)));

// ---- workspace layout (bf16 elems). All matrices stored as A-fragments for
// the TRANSPOSED GEMM  C^T[feature][batch] = W^T @ act^T :
//   frag(mt, kt, lane, j) at ((mt*KT + kt)*512 + lane*8 + j)
//   value = W[kappa][16*mt + (lane&15)]
// For weights consuming register-resident activations (Whp, Wm, Whpost, Wr1):
//   kappa = 32*kt + 16*(j>>2) + 4*(lane>>4) + (j&3)  [pi-permutation: B-frag ==
//   accumulator contents of the producing stage]. For Wcp (consumes x):
//   kappa = 32*kt + 8*(lane>>4) + j (natural).
#define OFF_HP 0
#define OFF_CP 65536
#define OFF_M  81920
#define OFF_PO 212992
#define OFF_R1 278528
#define TOT    344064

__global__ __launch_bounds__(256) void pack_weights(
    const float* __restrict__ Whp, const float* __restrict__ Wm,
    const float* __restrict__ Wcp, const float* __restrict__ Whpost,
    const float* __restrict__ Wr1, __bf16* __restrict__ wsp) {
  int id = blockIdx.x * 256 + threadIdx.x;
  if (id >= TOT) return;
  int j = id & 7, lane = (id >> 3) & 63;
  int lq = lane >> 4, l15 = lane & 15;
  int rel, KT; const float* W; bool perm = true;
  if (id < OFF_CP)      { rel = id;          KT = 8;  W = Whp; }
  else if (id < OFF_M)  { rel = id - OFF_CP; KT = 2;  W = Wcp; perm = false; }
  else if (id < OFF_PO) { rel = id - OFF_M;  KT = 16; W = Wm; }
  else if (id < OFF_R1) { rel = id - OFF_PO; KT = 8;  W = Whpost; }
  else                  { rel = id - OFF_R1; KT = 8;  W = Wr1; }
  int ktm = rel >> 9;
  int kt = ktm % KT, mt = ktm / KT;
  int phi = 16 * mt + l15;
  int kk;
  if (perm) {
    int kb = (kt >= 8) ? kt - 8 : kt;          // only mesh has kt>=8
    kk = 32 * kb + 16 * (j >> 2) + 4 * lq + (j & 3);
    if (kt >= 8) kk += 256;                    // cp half of the concat
  } else {
    kk = 32 * kt + 8 * lq + j;
  }
  wsp[id] = (__bf16)W[kk * 256 + phi];
}

__device__ __forceinline__ float tanh_fast(float x) {
  float t = __expf(2.0f * x);
  return 1.0f - __fdividef(2.0f, t + 1.0f);
}

#define MFMA(a, b, c) __builtin_amdgcn_mfma_f32_16x16x32_bf16((a), (b), (c), 0, 0, 0)

// tanh + pack this wave's two accumulators into ONE B-fragment (kt = wv).
// Pure in-lane: B[wv][j] = tanh(acc[j>>2][j&3]). Conflict-free ds_write_b128.
__device__ __forceinline__ void pack2(__bf16* region, int wv, int lane,
                                      const f32x4& a0, const f32x4& a1) {
  bf16x8 f;
  #pragma unroll
  for (int r = 0; r < 4; ++r) {
    f[r]     = (__bf16)tanh_fast(a0[r]);
    f[4 + r] = (__bf16)tanh_fast(a1[r]);
  }
  *(bf16x8*)(region + wv * 512 + lane * 8) = f;
}

__global__ __launch_bounds__(512)
__attribute__((amdgpu_waves_per_eu(2, 2)))   // force 256-VGPR budget: wm MUST stay resident
void rnn_seq(
    const float* __restrict__ x, const __bf16* __restrict__ wsp,
    const float* __restrict__ bhp, const float* __restrict__ bcp,
    const float* __restrict__ bm, const float* __restrict__ bhpost,
    const float* __restrict__ br1, const float* __restrict__ Wr2,
    const float* __restrict__ br2, float* __restrict__ out) {
  __shared__ __align__(16) __bf16 hB[8 * 512];   // h state as B-frags
  __shared__ __align__(16) __bf16 mB[16 * 512];  // [hpB | cpB] for mesh
  __shared__ __align__(16) __bf16 uB[8 * 512];   // mesh output
  __shared__ float lb[6 * 256];                  // bhp,bcp,bm,bhpost,br1,Wr2
  __shared__ float outp[128];

  const int tid  = threadIdx.x;
  const int wv   = tid >> 6;      // 0..7, owns m-tiles 2wv, 2wv+1
  const int lane = tid & 63;
  const int lq   = lane >> 4, l15 = lane & 15;
  const int n0   = blockIdx.x * 16;
  const int mt0  = 2 * wv;

  if (tid < 256) {
    lb[0 * 256 + tid] = bhp[tid];
    lb[1 * 256 + tid] = bcp[tid];
    lb[2 * 256 + tid] = bm[tid];
    lb[3 * 256 + tid] = bhpost[tid];
    lb[4 * 256 + tid] = br1[tid];
    lb[5 * 256 + tid] = Wr2[tid];
  }
  for (int i = tid; i < 8 * 512; i += 512) hB[i] = (__bf16)0.0f;  // h0 = 0
  const float br2v = br2[0];

  // bias/Wr2 accessor: element r of f32x4 <-> feature 16*mt + 4*lq + r
  #define BIAS(a, m) (*(const f32x4*)(lb + (a) * 256 + (m) * 16 + 4 * lq))
  const f32x4 w2a = *(const f32x4*)(Wr2 + mt0 * 16 + 4 * lq);
  const f32x4 w2b = *(const f32x4*)(Wr2 + (mt0 + 1) * 16 + 4 * lq);

  // ---- register-resident mesh weights: 32 frags = 128 VGPRs ----
  bf16x8 wm0[16], wm1[16];
  {
    const __bf16* mp = wsp + OFF_M + (size_t)(mt0 * 16) * 512 + lane * 8;
    #pragma unroll
    for (int kt = 0; kt < 16; ++kt) {
      wm0[kt] = *(const bf16x8*)(mp + kt * 512);
      wm1[kt] = *(const bf16x8*)(mp + (16 + kt) * 512);
    }
  }

  const __bf16* hp_p = wsp + OFF_HP + (size_t)(mt0 * 8) * 512 + lane * 8;
  const __bf16* r1_p = wsp + OFF_R1 + (size_t)(mt0 * 8) * 512 + lane * 8;
  const __bf16* cp_p = wsp + OFF_CP + (size_t)(mt0 * 2) * 512 + lane * 8;
  const __bf16* po_p = wsp + OFF_PO + (size_t)(mt0 * 8) * 512 + lane * 8;

  __syncthreads();

  // x for step t (re-prefetched each step during stage 2)
  const float* xbase = x + (size_t)(n0 + l15) * 64 + 8 * lq;
  f32x4 xr0 = *(const f32x4*)(xbase);
  f32x4 xr1 = *(const f32x4*)(xbase + 4);
  f32x4 xr2 = *(const f32x4*)(xbase + 32);
  f32x4 xr3 = *(const f32x4*)(xbase + 36);

  // hp fragments for step 0, depth-8 window
  bf16x8 hpb[8];
  #pragma unroll
  for (int p = 0; p < 8; ++p) hpb[p] = *(const bf16x8*)(hp_p + p * 512);

  for (int t = 0; t < TT; ++t) {
    bf16x8 Bx0, Bx1;
    #pragma unroll
    for (int j = 0; j < 4; ++j) {
      Bx0[j] = (__bf16)xr0[j]; Bx0[4 + j] = (__bf16)xr1[j];
      Bx1[j] = (__bf16)xr2[j]; Bx1[4 + j] = (__bf16)xr3[j];
    }

    // ---- stage 1: hp = h@Whp + bhp ; cp = x@Wcp + bcp ----
    bf16x8 cpb[4];
    #pragma unroll
    for (int p = 0; p < 4; ++p) cpb[p] = *(const bf16x8*)(cp_p + p * 512);
    bf16x8 Bh[8];
    #pragma unroll
    for (int kt = 0; kt < 8; ++kt)
      Bh[kt] = *(const bf16x8*)(hB + kt * 512 + lane * 8);

    f32x4 ah0 = BIAS(0, mt0), ah1 = BIAS(0, mt0 + 1);
    #pragma unroll
    for (int i = 0; i < 16; ++i) {       // frag i = (mt0 + (i>>3), kt = i&7)
      bf16x8 a = hpb[i & 7];
      if (i < 8) ah0 = MFMA(a, Bh[i & 7], ah0);
      else       ah1 = MFMA(a, Bh[i & 7], ah1);
      if (i + 8 < 16) hpb[i & 7] = *(const bf16x8*)(hp_p + (i + 8) * 512);
    }
    f32x4 ac0 = BIAS(1, mt0), ac1 = BIAS(1, mt0 + 1);
    ac0 = MFMA(cpb[0], Bx0, ac0); ac0 = MFMA(cpb[1], Bx1, ac0);
    ac1 = MFMA(cpb[2], Bx0, ac1); ac1 = MFMA(cpb[3], Bx1, ac1);

    pack2(mB,           wv, lane, ah0, ah1);
    pack2(mB + 8 * 512, wv, lane, ac0, ac1);
    __syncthreads();  // B1

    // ---- stage 2: u = cat@Wm + bm (wm resident, zero loads) ;
    //               r1 = h@Wr1 + br1 (reuses register Bh; loads hide under MFMAs)
    bf16x8 r1b[8];
    #pragma unroll
    for (int p = 0; p < 8; ++p) r1b[p] = *(const bf16x8*)(r1_p + p * 512);
    f32x4 am0 = BIAS(2, mt0), am1 = BIAS(2, mt0 + 1);
    f32x4 ar0 = BIAS(4, mt0), ar1 = BIAS(4, mt0 + 1);
    #pragma unroll
    for (int i = 0; i < 16; ++i) {
      bf16x8 Bm = *(const bf16x8*)(mB + i * 512 + lane * 8);
      am0 = MFMA(wm0[i], Bm, am0);
      am1 = MFMA(wm1[i], Bm, am1);
      bf16x8 a = r1b[i & 7];
      if (i < 8) ar0 = MFMA(a, Bh[i & 7], ar0);
      else       ar1 = MFMA(a, Bh[i & 7], ar1);
      if (i + 8 < 16) r1b[i & 7] = *(const bf16x8*)(r1_p + (i + 8) * 512);
    }
    // prefetch: first half of po frags + next step's x (drain hidden by B2)
    bf16x8 pob[8];
    #pragma unroll
    for (int p = 0; p < 8; ++p) pob[p] = *(const bf16x8*)(po_p + p * 512);
    {
      int tn = (t + 1 < TT) ? t + 1 : TT - 1;
      const float* xp = xbase + (size_t)tn * NB * 64;
      xr0 = *(const f32x4*)(xp);      xr1 = *(const f32x4*)(xp + 4);
      xr2 = *(const f32x4*)(xp + 32); xr3 = *(const f32x4*)(xp + 36);
    }
    {
      float p = 0.f;
      #pragma unroll
      for (int r = 0; r < 4; ++r)
        p += fmaxf(ar0[r], 0.f) * w2a[r] + fmaxf(ar1[r], 0.f) * w2b[r];
      p += __shfl_xor(p, 16, 64);
      p += __shfl_xor(p, 32, 64);
      if (lane < 16) outp[wv * 16 + lane] = p;
    }
    pack2(uB, wv, lane, am0, am1);
    __syncthreads();  // B2

    // ---- stage 3: h = tanh(u @ Whpost + bhpost) ; store out[t-1] ----
    if (t > 0 && tid < 16) {
      float s = br2v;
      #pragma unroll
      for (int w = 0; w < 8; ++w) s += outp[w * 16 + tid];
      out[(size_t)(t - 1) * NB + n0 + tid] = s;
    }
    bf16x8 Bu[8];
    #pragma unroll
    for (int kt = 0; kt < 8; ++kt)
      Bu[kt] = *(const bf16x8*)(uB + kt * 512 + lane * 8);
    f32x4 ap0 = BIAS(3, mt0), ap1 = BIAS(3, mt0 + 1);
    #pragma unroll
    for (int i = 0; i < 16; ++i) {
      bf16x8 a = pob[i & 7];
      if (i < 8) ap0 = MFMA(a, Bu[i & 7], ap0);
      else       ap1 = MFMA(a, Bu[i & 7], ap1);
      if (i + 8 < 16) pob[i & 7] = *(const bf16x8*)(po_p + (i + 8) * 512);
    }
    pack2(hB, wv, lane, ap0, ap1);
    // prefetch next step's hp window (drain hidden by B3)
    #pragma unroll
    for (int p = 0; p < 8; ++p) hpb[p] = *(const bf16x8*)(hp_p + p * 512);
    __syncthreads();  // B3
  }

  // ---- tail: regressor on final h ----
  {
    bf16x8 Bh[8];
    #pragma unroll
    for (int kt = 0; kt < 8; ++kt)
      Bh[kt] = *(const bf16x8*)(hB + kt * 512 + lane * 8);
    f32x4 ar0 = BIAS(4, mt0), ar1 = BIAS(4, mt0 + 1);
    bf16x8 r1b[8];
    #pragma unroll
    for (int p = 0; p < 8; ++p) r1b[p] = *(const bf16x8*)(r1_p + p * 512);
    #pragma unroll
    for (int i = 0; i < 16; ++i) {
      bf16x8 a = r1b[i & 7];
      if (i < 8) ar0 = MFMA(a, Bh[i & 7], ar0);
      else       ar1 = MFMA(a, Bh[i & 7], ar1);
      if (i + 8 < 16) r1b[i & 7] = *(const bf16x8*)(r1_p + (i + 8) * 512);
    }
    float p = 0.f;
    #pragma unroll
    for (int r = 0; r < 4; ++r)
      p += fmaxf(ar0[r], 0.f) * w2a[r] + fmaxf(ar1[r], 0.f) * w2b[r];
    p += __shfl_xor(p, 16, 64);
    p += __shfl_xor(p, 32, 64);
    if (lane < 16) outp[wv * 16 + lane] = p;
    __syncthreads();
    if (tid < 16) {
      float s = br2v;
      #pragma unroll
      for (int w = 0; w < 8; ++w) s += outp[w * 16 + tid];
      out[(size_t)(TT - 1) * NB + n0 + tid] = s;
    }
  }
}

extern "C" void kernel_launch(void* const* d_in, const int* in_sizes, int n_in,
                              void* d_out, int out_size, void* d_ws, size_t ws_size,
                              hipStream_t stream) {
  const float* x      = (const float*)d_in[0];
  const float* Whp    = (const float*)d_in[1];
  const float* bhp    = (const float*)d_in[2];
  const float* Wcp    = (const float*)d_in[3];
  const float* bcp    = (const float*)d_in[4];
  const float* Wm     = (const float*)d_in[5];
  const float* bm     = (const float*)d_in[6];
  const float* Whpost = (const float*)d_in[7];
  const float* bhpost = (const float*)d_in[8];
  const float* Wr1    = (const float*)d_in[9];
  const float* br1    = (const float*)d_in[10];
  const float* Wr2    = (const float*)d_in[11];
  const float* br2    = (const float*)d_in[12];
  __bf16* wsp = (__bf16*)d_ws;
  float*  out = (float*)d_out;

  if (ws_size < (size_t)TOT * sizeof(__bf16)) return;

  pack_weights<<<(TOT + 255) / 256, 256, 0, stream>>>(Whp, Wm, Wcp, Whpost, Wr1, wsp);
  rnn_seq<<<64, 512, 0, stream>>>(x, wsp, bhp, bcp, bm, bhpost, br1, Wr2, br2, out);
}